// Round 8
// baseline (735.411 us; speedup 1.0000x reference)
//
#include <hip/hip_runtime.h>
#include <math.h>

// Problem: x[B=32][C=256][HW=3136] fp32, omega[256][8]; rank q=8, niter=2.
// y = A Q2 Q2^T per spatial m, via Gram reformulation (G = A^T A, 32x32).
// Round-8: k1a+k1b fused via last-block-done (device-fence + atomic counter);
// the last slice-block of each m-tile runs the CholQR2 solve inline -> Q2.
#define HW   3136
#define NB   32
#define NC   256
#define TM   16              // m's per block in streaming kernels
#define CC   8               // c's per LDS chunk
#define LDP  36              // padded b-stride in transposed slab
#define SLABC (TM * LDP)     // 576 floats per cc
#define SLABF (CC * SLABC)   // 4608 floats per buffer

#define NS   4               // c-slices for partial Gram
#define CSL  (NC / NS)       // 64 c per slice
#define NCH  (CSL / CC)      // 8 chunks per slice
#define GK   1280            // record floats per (slice,m): 1024 G + 256 Y
#define PST  68              // k2: P lds stride per m

// ---- solve LDS layout (mi in 0..15, odd strides -> bank-spread) ----
// YT max idx 15*265+7*33+31 = 4237 < 4240; WT at +4240; SS at +8480 (16*65)
#define YT_(mi,b,q) Sm[(mi)*265 + (q)*33 + (b)]
#define WT_(mi,b,q) Sm[4240 + (mi)*265 + (q)*33 + (b)]
#define SS_(mi,k)   Sm[8480 + (mi)*65 + (k)]
#define SMEMF 9520           // >= 2*SLABF (9216): slab and solve share Sm

__host__ __device__ constexpr int TRI(int i, int j) { return i*8 - (i*(i+1))/2 + j; }

// ---- 512-thread staging: global (m-coalesced float4) -> transposed slab [cc][m][b] ----
__device__ __forceinline__ void stage_load512(float4* r, const float* __restrict__ xg,
                                              int c0, int m0, int t) {
#pragma unroll
  for (int i = 0; i < 2; ++i) {
    int id = t + i * 512;                 // 0..1023 float4 per chunk
    int cc = id >> 7, b = (id >> 2) & 31, mq = id & 3;
    r[i] = *reinterpret_cast<const float4*>(
        xg + (size_t)(b * NC + c0 + cc) * HW + m0 + mq * 4);
  }
}
__device__ __forceinline__ void stage_write_t(const float4* r, float* sl, int t) {
#pragma unroll
  for (int i = 0; i < 2; ++i) {
    int id = t + i * 512;
    int cc = id >> 7, b = (id >> 2) & 31, mq = id & 3;
    float* p = sl + cc * SLABC + (mq * 4) * LDP + b;
    p[0 * LDP] = r[i].x;
    p[1 * LDP] = r[i].y;
    p[2 * LDP] = r[i].z;
    p[3 * LDP] = r[i].w;
  }
}

// ---- replicated 8x8 Cholesky from SS (upper R; diag slot holds 1/R[i][i]) ----
__device__ __forceinline__ void chol8(const float* __restrict__ Sm, int mi, float* Rl) {
#pragma unroll
  for (int i = 0; i < 8; ++i) {
    float d = SS_(mi, i * 8 + i);
#pragma unroll
    for (int k = 0; k < 8; ++k) {
      if (k < i) { float rk = Rl[TRI(k, i)]; d = fmaf(-rk, rk, d); }
    }
    float rii = sqrtf(fmaxf(d, 1e-30f));
    float inv = 1.0f / rii;
    Rl[TRI(i, i)] = inv;
#pragma unroll
    for (int j = 0; j < 8; ++j) {
      if (j > i) {
        float v = SS_(mi, i * 8 + j);
#pragma unroll
        for (int k = 0; k < 8; ++k) {
          if (k < i) v = fmaf(-Rl[TRI(k, i)], Rl[TRI(k, j)], v);
        }
        Rl[TRI(i, j)] = v * inv;
      }
    }
  }
}

// row r: dst_row = src_row * R^{-1} (forward substitution through upper R)
__device__ __forceinline__ void trsm1row(const float* __restrict__ srcB, float* __restrict__ dstB,
                                         int mi, int r, const float* Rl) {
  float yv[8], qv[8];
#pragma unroll
  for (int q = 0; q < 8; ++q) yv[q] = srcB[mi * 265 + q * 33 + r];
#pragma unroll
  for (int j = 0; j < 8; ++j) {
    float a = yv[j];
#pragma unroll
    for (int k = 0; k < 8; ++k) {
      if (k < j) a = fmaf(-qv[k], Rl[TRI(k, j)], a);
    }
    qv[j] = a * Rl[TRI(j, j)];
  }
#pragma unroll
  for (int q = 0; q < 8; ++q) dstB[mi * 265 + q * 33 + r] = qv[q];
}

// one CholeskyQR pass in-place on YT (32 threads per m; thread owns row r)
__device__ __forceinline__ void cholqr32(float* __restrict__ Sm, int mi, int r) {
#pragma unroll
  for (int e = 0; e < 2; ++e) {
    int idx = r + e * 32, i = idx >> 3, j = idx & 7;
    float s = 0.f;
#pragma unroll
    for (int b = 0; b < 32; ++b) s = fmaf(YT_(mi, b, i), YT_(mi, b, j), s);
    SS_(mi, idx) = s;
  }
  __syncthreads();
  float Rl[36];
  chol8(Sm, mi, Rl);
  trsm1row(Sm, Sm, mi, r, Rl);
  __syncthreads();
}

// ============ K1 (fused): partial Gram per c-slice; last slice-block solves ============
__global__ __launch_bounds__(512, 4) void tsvd_k1(const float* __restrict__ x,
                                                  const float* __restrict__ omega,
                                                  float* __restrict__ Gp,
                                                  float* __restrict__ Qws,
                                                  int* __restrict__ cnt) {
  __shared__ float Sm[SMEMF];      // streaming slab (2*SLABF) / solve buffers (union)
  __shared__ int isLast;
  const int t = threadIdx.x;
  const int mi = t & 15, g = t >> 4;
  const int rg = g >> 3, bj = g & 7;
  const int r0 = rg * 8, b0 = bj * 4;
  const int s = blockIdx.x & (NS - 1);
  const int mt = blockIdx.x / NS;
  const int m0 = mt * TM, m = m0 + mi;
  const int c0 = s * CSL;

  // ---- streaming phase: partial G (8r x 4b register tile) + partial Y ----
  float Gt[8][4], Yt[8];
#pragma unroll
  for (int i = 0; i < 8; ++i) {
    Yt[i] = 0.f;
#pragma unroll
    for (int j = 0; j < 4; ++j) Gt[i][j] = 0.f;
  }

  float4 st[2];
  stage_load512(st, x, c0, m0, t);
  stage_write_t(st, Sm, t);
  for (int ch = 0; ch < NCH; ++ch) {
    if (ch + 1 < NCH) stage_load512(st, x, c0 + (ch + 1) * CC, m0, t);
    __syncthreads();
    const float* cur = Sm + (ch & 1) * SLABF;
#pragma unroll
    for (int cc = 0; cc < CC; ++cc) {
      const int c = c0 + ch * CC + cc;
      const float* v = cur + cc * SLABC + mi * LDP;
      float4 ra = *reinterpret_cast<const float4*>(v + r0);
      float4 rb = *reinterpret_cast<const float4*>(v + r0 + 4);
      float4 cb = *reinterpret_cast<const float4*>(v + b0);
      const float w = omega[c * 8 + bj];
      float rv[8] = {ra.x, ra.y, ra.z, ra.w, rb.x, rb.y, rb.z, rb.w};
#pragma unroll
      for (int i = 0; i < 8; ++i) {
        Gt[i][0] = fmaf(rv[i], cb.x, Gt[i][0]);
        Gt[i][1] = fmaf(rv[i], cb.y, Gt[i][1]);
        Gt[i][2] = fmaf(rv[i], cb.z, Gt[i][2]);
        Gt[i][3] = fmaf(rv[i], cb.w, Gt[i][3]);
        Yt[i]    = fmaf(rv[i], w,    Yt[i]);
      }
    }
    if (ch + 1 < NCH) stage_write_t(st, Sm + ((ch + 1) & 1) * SLABF, t);
  }

  // ---- store partial record (record-major, same layout as round 6/7) ----
  {
    float4* rec = reinterpret_cast<float4*>(Gp + ((size_t)s * HW + m) * GK);
#pragma unroll
    for (int i = 0; i < 8; ++i)
      rec[(r0 + i) * 8 + bj] = make_float4(Gt[i][0], Gt[i][1], Gt[i][2], Gt[i][3]);
    float* recf = Gp + ((size_t)s * HW + m) * GK + 1024;
#pragma unroll
    for (int i = 0; i < 8; ++i)
      recf[(r0 + i) * 8 + bj] = Yt[i];
  }

  // ---- last-block election (release: stores -> fence -> sync -> atomic) ----
  __threadfence();                               // flush this block's stores device-wide
  __syncthreads();                               // all threads' stores fenced
  if (t == 0) isLast = (atomicAdd(&cnt[mt], 1) == NS - 1) ? 1 : 0;
  __syncthreads();                               // also: slab reads done -> Sm reusable
  if (!isLast) return;
  __threadfence();                               // acquire: see all 4 slices' stores

  // ---- solve phase (verbatim k1b math; 32 thr/m, 16 m, r = g) ----
  const int r = g;
  float G0[32], Y0[8];
#pragma unroll
  for (int b = 0; b < 32; ++b) G0[b] = 0.f;
#pragma unroll
  for (int q = 0; q < 8; ++q) Y0[q] = 0.f;
#pragma unroll
  for (int s2 = 0; s2 < NS; ++s2) {
    const float4* rec = reinterpret_cast<const float4*>(Gp + ((size_t)s2 * HW + m) * GK);
#pragma unroll
    for (int k = 0; k < 8; ++k) {
      float4 v = rec[r * 8 + k];
      G0[4 * k + 0] += v.x;
      G0[4 * k + 1] += v.y;
      G0[4 * k + 2] += v.z;
      G0[4 * k + 3] += v.w;
    }
    float4 y0 = rec[256 + r * 2 + 0];
    float4 y1 = rec[256 + r * 2 + 1];
    Y0[0] += y0.x; Y0[1] += y0.y; Y0[2] += y0.z; Y0[3] += y0.w;
    Y0[4] += y1.x; Y0[5] += y1.y; Y0[6] += y1.z; Y0[7] += y1.w;
  }

#pragma unroll
  for (int q = 0; q < 8; ++q) YT_(mi, r, q) = Y0[q];
  __syncthreads();

#pragma unroll
  for (int it = 0; it < 3; ++it) {
    cholqr32(Sm, mi, r);        // CholQR2: orthonormal basis of span(Y)
    cholqr32(Sm, mi, r);
    if (it < 2) {
      // U = G*Q -> WT
      float u[8];
#pragma unroll
      for (int q = 0; q < 8; ++q) {
        float a = 0.f;
#pragma unroll
        for (int b = 0; b < 32; ++b) a = fmaf(G0[b], YT_(mi, b, q), a);
        u[q] = a;
      }
#pragma unroll
      for (int q = 0; q < 8; ++q) WT_(mi, r, q) = u[q];
      __syncthreads();
      // T = Q^T G Q -> SS
#pragma unroll
      for (int e = 0; e < 2; ++e) {
        int idx = r + e * 32, i2 = idx >> 3, j2 = idx & 7;
        float a = 0.f;
#pragma unroll
        for (int b = 0; b < 32; ++b) a = fmaf(YT_(mi, b, i2), WT_(mi, b, j2), a);
        SS_(mi, idx) = a;
      }
      __syncthreads();
      // W = Q R^{-1} -> WT   (implicit qr(A*Q))
      {
        float Rl[36];
        chol8(Sm, mi, Rl);
        trsm1row(Sm, Sm + 4240, mi, r, Rl);
      }
      __syncthreads();
      // Y_next = G*W -> YT
#pragma unroll
      for (int q = 0; q < 8; ++q) {
        float a = 0.f;
#pragma unroll
        for (int b = 0; b < 32; ++b) a = fmaf(G0[b], WT_(mi, b, q), a);
        u[q] = a;
      }
#pragma unroll
      for (int q = 0; q < 8; ++q) YT_(mi, r, q) = u[q];
      __syncthreads();
    }
  }

  // store Q2 row r: Qws[m*256 + r*8 + q]
  float q0[8];
#pragma unroll
  for (int q = 0; q < 8; ++q) q0[q] = YT_(mi, r, q);
  float4* qrec = reinterpret_cast<float4*>(Qws + (size_t)m * 256);
  qrec[r * 2 + 0] = make_float4(q0[0], q0[1], q0[2], q0[3]);
  qrec[r * 2 + 1] = make_float4(q0[4], q0[5], q0[6], q0[7]);
}

// ============ K2: P = A Q2 (stage1), y = P Q2^T (stage2), per m ============
__global__ __launch_bounds__(512, 4) void tsvd_k2(const float* __restrict__ x,
                                                  const float* __restrict__ Qws,
                                                  float* __restrict__ y) {
  __shared__ float Sm2[2 * SLABF + TM * PST];
  float* Pl = Sm2 + 2 * SLABF;
  const int t = threadIdx.x;
  const int mi = t & 15, g = t >> 4;
  const int cj = g & 7, qd = g >> 3;
  const int r = g;
  const int bid = blockIdx.x;
  const int mt = bid % 196, cq = bid / 196;     // 196 m-tiles x 8 c-slices of 32
  const int m0 = mt * TM, m = m0 + mi;
  const int cbase = cq * 32;

  // Q2 columns (2qd, 2qd+1) for stage1; Q2 row r for stage2
  const float* qrec = Qws + (size_t)m * 256;
  float Qc0[32], Qc1[32];
#pragma unroll
  for (int b = 0; b < 32; ++b) {
    float2 v = reinterpret_cast<const float2*>(qrec)[b * 4 + qd];
    Qc0[b] = v.x; Qc1[b] = v.y;
  }
  float Qr[8];
  {
    float4 a = reinterpret_cast<const float4*>(qrec)[r * 2 + 0];
    float4 b4 = reinterpret_cast<const float4*>(qrec)[r * 2 + 1];
    Qr[0] = a.x; Qr[1] = a.y; Qr[2] = a.z; Qr[3] = a.w;
    Qr[4] = b4.x; Qr[5] = b4.y; Qr[6] = b4.z; Qr[7] = b4.w;
  }

  float4 st[2];
  stage_load512(st, x, cbase, m0, t);
  stage_write_t(st, Sm2, t);
  for (int ch = 0; ch < 4; ++ch) {
    if (ch + 1 < 4) stage_load512(st, x, cbase + (ch + 1) * CC, m0, t);
    __syncthreads();                      // slab(ch) ready; P free
    const float* cur = Sm2 + (ch & 1) * SLABF;
    // ---- stage1: P[cj][2qd+e] = sum_b x[b][c] * Q2[b][2qd+e] ----
    {
      const float* v = cur + cj * SLABC + mi * LDP;
      float p0 = 0.f, p1 = 0.f;
#pragma unroll
      for (int k = 0; k < 8; ++k) {
        float4 xb = *reinterpret_cast<const float4*>(v + 4 * k);
        p0 = fmaf(xb.x, Qc0[4 * k + 0], p0);
        p0 = fmaf(xb.y, Qc0[4 * k + 1], p0);
        p0 = fmaf(xb.z, Qc0[4 * k + 2], p0);
        p0 = fmaf(xb.w, Qc0[4 * k + 3], p0);
        p1 = fmaf(xb.x, Qc1[4 * k + 0], p1);
        p1 = fmaf(xb.y, Qc1[4 * k + 1], p1);
        p1 = fmaf(xb.z, Qc1[4 * k + 2], p1);
        p1 = fmaf(xb.w, Qc1[4 * k + 3], p1);
      }
      *reinterpret_cast<float2*>(Pl + mi * PST + cj * 8 + 2 * qd) = make_float2(p0, p1);
    }
    if (ch + 1 < 4) stage_write_t(st, Sm2 + ((ch + 1) & 1) * SLABF, t);
    __syncthreads();                      // P visible
    // ---- stage2: y[r][c] = sum_q Qr[q] * P[c][q], 8 c's ----
    const float* Pm = Pl + mi * PST;
#pragma unroll
    for (int c2 = 0; c2 < 8; ++c2) {
      float4 pa = *reinterpret_cast<const float4*>(Pm + c2 * 8);
      float4 pb = *reinterpret_cast<const float4*>(Pm + c2 * 8 + 4);
      float a = 0.f;
      a = fmaf(Qr[0], pa.x, a);
      a = fmaf(Qr[1], pa.y, a);
      a = fmaf(Qr[2], pa.z, a);
      a = fmaf(Qr[3], pa.w, a);
      a = fmaf(Qr[4], pb.x, a);
      a = fmaf(Qr[5], pb.y, a);
      a = fmaf(Qr[6], pb.z, a);
      a = fmaf(Qr[7], pb.w, a);
      const int c = cbase + ch * CC + c2;
      y[((size_t)r * NC + c) * HW + m] = a;
    }
  }
}

extern "C" void kernel_launch(void* const* d_in, const int* in_sizes, int n_in,
                              void* d_out, int out_size, void* d_ws, size_t ws_size,
                              hipStream_t stream) {
  const float* x     = (const float*)d_in[0];   // 32*256*3136 fp32
  const float* omega = (const float*)d_in[1];   // 256*8 fp32
  float* y   = (float*)d_out;                   // 32*256*3136 fp32
  float* Qws = (float*)d_ws;                    // 3136*256*4 = 3.21 MB
  int*   cnt = (int*)((char*)d_ws + (4u << 20)); // past Qws, 196 ints (ws >= 12.8MB proven)
  // Partial Gram scratch in d_out: 4*3136*1280*4B = 64.2 MB < 102.8 MB;
  // consumed by the in-kernel solver, then k2 overwrites all of d_out with y.
  float* Gp  = (float*)d_out;

  hipMemsetAsync(cnt, 0, 196 * sizeof(int), stream);   // counters must start at 0
  tsvd_k1<<<196 * NS, 512, 0, stream>>>(x, omega, Gp, Qws, cnt);
  tsvd_k2<<<196 * 8, 512, 0, stream>>>(x, Qws, y);
}

// Round 10
// 288.084 us; speedup vs baseline: 2.5528x; 2.5528x over previous
//
#include <hip/hip_runtime.h>
#include <math.h>

// Problem: x[B=32][C=256][HW=3136] fp32, omega[256][8]; rank q=8, niter=2.
// y = A Q2 Q2^T per spatial m, via Gram reformulation (G = A^T A, 32x32).
// Round-9: revert round-8 fusion (threadfence = L2 writeback storm on CDNA4).
// k1a/k1b = round-6 form. k2 rebuilt with TM=32 (128B global segments).
#define HW   3136
#define NB   32
#define NC   256
#define TM   16              // k1a m-tile
#define CC   8               // k1a c's per chunk
#define LDP  36              // padded b-stride in transposed slab
#define SLABC (TM * LDP)     // 576 floats per cc (k1a)
#define SLABF (CC * SLABC)   // 4608 floats per buffer (k1a)

#define NS   4               // c-slices for partial Gram
#define CSL  (NC / NS)       // 64 c per slice
#define NCH  (CSL / CC)      // 8 chunks per slice
#define GK   1280            // record floats per (slice,m): 1024 G + 256 Y

// ---- k2 geometry (TM2=32 m per block, CC2=4 c per chunk) ----
#define TM2   32
#define CC2   4
#define SLABC2 (TM2 * LDP)   // 1152 floats per cc
#define SLABF2 (CC2 * SLABC2) // 4608 floats per buffer
#define PST2  36             // P stride per m (32 data + pad)

// ---- k1b (solve) LDS layout: mi in 0..7, odd strides -> bank-spread ----
#define YT_(mi,b,q) Sm[(mi)*265 + (q)*33 + (b)]
#define WT_(mi,b,q) Sm[4240 + (mi)*265 + (q)*33 + (b)]
#define SS_(mi,k)   Sm[8480 + (mi)*65 + (k)]
#define SMEMF 9520

__host__ __device__ constexpr int TRI(int i, int j) { return i*8 - (i*(i+1))/2 + j; }

// ---- k1a staging: global (m-coalesced float4) -> transposed slab [cc][m][b] ----
__device__ __forceinline__ void stage_load512(float4* r, const float* __restrict__ xg,
                                              int c0, int m0, int t) {
#pragma unroll
  for (int i = 0; i < 2; ++i) {
    int id = t + i * 512;                 // 0..1023 float4 per chunk
    int cc = id >> 7, b = (id >> 2) & 31, mq = id & 3;
    r[i] = *reinterpret_cast<const float4*>(
        xg + (size_t)(b * NC + c0 + cc) * HW + m0 + mq * 4);
  }
}
__device__ __forceinline__ void stage_write_t(const float4* r, float* sl, int t) {
#pragma unroll
  for (int i = 0; i < 2; ++i) {
    int id = t + i * 512;
    int cc = id >> 7, b = (id >> 2) & 31, mq = id & 3;
    float* p = sl + cc * SLABC + (mq * 4) * LDP + b;
    p[0 * LDP] = r[i].x;
    p[1 * LDP] = r[i].y;
    p[2 * LDP] = r[i].z;
    p[3 * LDP] = r[i].w;
  }
}

// ---- k2 staging: TM2=32 -> 128B contiguous per (b,c) row ----
__device__ __forceinline__ void stage_load_k2(float4* r, const float* __restrict__ xg,
                                              int c0, int m0, int t) {
#pragma unroll
  for (int i = 0; i < 2; ++i) {
    int id = t + i * 512;                 // 0..1023 float4 per chunk
    int row = id >> 3, f = id & 7;        // row = cc*32+b; 8 float4 = 32 m per row
    int cc = row >> 5, b = row & 31;
    r[i] = *reinterpret_cast<const float4*>(
        xg + (size_t)(b * NC + c0 + cc) * HW + m0 + f * 4);
  }
}
__device__ __forceinline__ void stage_write_k2(const float4* r, float* sl, int t) {
#pragma unroll
  for (int i = 0; i < 2; ++i) {
    int id = t + i * 512;
    int row = id >> 3, f = id & 7;
    int cc = row >> 5, b = row & 31;
    float* p = sl + cc * SLABC2 + (f * 4) * LDP + b;
    p[0 * LDP] = r[i].x;
    p[1 * LDP] = r[i].y;
    p[2 * LDP] = r[i].z;
    p[3 * LDP] = r[i].w;
  }
}

// ---- replicated 8x8 Cholesky from SS (upper R; diag slot holds 1/R[i][i]) ----
__device__ __forceinline__ void chol8(const float* __restrict__ Sm, int mi, float* Rl) {
#pragma unroll
  for (int i = 0; i < 8; ++i) {
    float d = SS_(mi, i * 8 + i);
#pragma unroll
    for (int k = 0; k < 8; ++k) {
      if (k < i) { float rk = Rl[TRI(k, i)]; d = fmaf(-rk, rk, d); }
    }
    float rii = sqrtf(fmaxf(d, 1e-30f));
    float inv = 1.0f / rii;
    Rl[TRI(i, i)] = inv;
#pragma unroll
    for (int j = 0; j < 8; ++j) {
      if (j > i) {
        float v = SS_(mi, i * 8 + j);
#pragma unroll
        for (int k = 0; k < 8; ++k) {
          if (k < i) v = fmaf(-Rl[TRI(k, i)], Rl[TRI(k, j)], v);
        }
        Rl[TRI(i, j)] = v * inv;
      }
    }
  }
}

// row r: dst_row = src_row * R^{-1} (forward substitution through upper R)
__device__ __forceinline__ void trsm1row(const float* __restrict__ srcB, float* __restrict__ dstB,
                                         int mi, int r, const float* Rl) {
  float yv[8], qv[8];
#pragma unroll
  for (int q = 0; q < 8; ++q) yv[q] = srcB[mi * 265 + q * 33 + r];
#pragma unroll
  for (int j = 0; j < 8; ++j) {
    float a = yv[j];
#pragma unroll
    for (int k = 0; k < 8; ++k) {
      if (k < j) a = fmaf(-qv[k], Rl[TRI(k, j)], a);
    }
    qv[j] = a * Rl[TRI(j, j)];
  }
#pragma unroll
  for (int q = 0; q < 8; ++q) dstB[mi * 265 + q * 33 + r] = qv[q];
}

// one CholeskyQR pass in-place on YT (32 threads per m; thread owns row r)
__device__ __forceinline__ void cholqr32(float* __restrict__ Sm, int mi, int r) {
#pragma unroll
  for (int e = 0; e < 2; ++e) {
    int idx = r + e * 32, i = idx >> 3, j = idx & 7;
    float s = 0.f;
#pragma unroll
    for (int b = 0; b < 32; ++b) s = fmaf(YT_(mi, b, i), YT_(mi, b, j), s);
    SS_(mi, idx) = s;
  }
  __syncthreads();
  float Rl[36];
  chol8(Sm, mi, Rl);
  trsm1row(Sm, Sm, mi, r, Rl);
  __syncthreads();
}

// ============ K1a: partial Gram (8r x 4b register tile) + partial Y0 ============
__global__ __launch_bounds__(512, 4) void tsvd_k1a(const float* __restrict__ x,
                                                   const float* __restrict__ omega,
                                                   float* __restrict__ Gp) {
  __shared__ float Sm[2 * SLABF];
  const int t = threadIdx.x;
  const int mi = t & 15, g = t >> 4;
  const int rg = g >> 3, bj = g & 7;
  const int r0 = rg * 8, b0 = bj * 4;
  const int s = blockIdx.x & (NS - 1);
  const int mt = blockIdx.x / NS;
  const int m0 = mt * TM, m = m0 + mi;
  const int c0 = s * CSL;

  float Gt[8][4], Yt[8];
#pragma unroll
  for (int i = 0; i < 8; ++i) {
    Yt[i] = 0.f;
#pragma unroll
    for (int j = 0; j < 4; ++j) Gt[i][j] = 0.f;
  }

  float4 st[2];
  stage_load512(st, x, c0, m0, t);
  stage_write_t(st, Sm, t);
  for (int ch = 0; ch < NCH; ++ch) {
    if (ch + 1 < NCH) stage_load512(st, x, c0 + (ch + 1) * CC, m0, t);
    __syncthreads();
    const float* cur = Sm + (ch & 1) * SLABF;
#pragma unroll
    for (int cc = 0; cc < CC; ++cc) {
      const int c = c0 + ch * CC + cc;
      const float* v = cur + cc * SLABC + mi * LDP;
      float4 ra = *reinterpret_cast<const float4*>(v + r0);
      float4 rb = *reinterpret_cast<const float4*>(v + r0 + 4);
      float4 cb = *reinterpret_cast<const float4*>(v + b0);
      const float w = omega[c * 8 + bj];
      float rv[8] = {ra.x, ra.y, ra.z, ra.w, rb.x, rb.y, rb.z, rb.w};
#pragma unroll
      for (int i = 0; i < 8; ++i) {
        Gt[i][0] = fmaf(rv[i], cb.x, Gt[i][0]);
        Gt[i][1] = fmaf(rv[i], cb.y, Gt[i][1]);
        Gt[i][2] = fmaf(rv[i], cb.z, Gt[i][2]);
        Gt[i][3] = fmaf(rv[i], cb.w, Gt[i][3]);
        Yt[i]    = fmaf(rv[i], w,    Yt[i]);
      }
    }
    if (ch + 1 < NCH) stage_write_t(st, Sm + ((ch + 1) & 1) * SLABF, t);
  }

  float4* rec = reinterpret_cast<float4*>(Gp + ((size_t)s * HW + m) * GK);
#pragma unroll
  for (int i = 0; i < 8; ++i)
    rec[(r0 + i) * 8 + bj] = make_float4(Gt[i][0], Gt[i][1], Gt[i][2], Gt[i][3]);
  float* recf = Gp + ((size_t)s * HW + m) * GK + 1024;
#pragma unroll
  for (int i = 0; i < 8; ++i)
    recf[(r0 + i) * 8 + bj] = Yt[i];
}

// ============ K1b: reduce slices -> CholQR2 chain -> Q2 (32x8 per m) ============
__global__ __launch_bounds__(256) void tsvd_k1b(const float* __restrict__ Gp,
                                                float* __restrict__ Qws) {
  __shared__ float Sm[SMEMF];
  const int t = threadIdx.x;
  const int r = t & 31, mi = t >> 5;            // 8 m per block, thread owns row r
  const int m0 = blockIdx.x * 8, m = m0 + mi;

  float G0[32], Y0[8];
#pragma unroll
  for (int b = 0; b < 32; ++b) G0[b] = 0.f;
#pragma unroll
  for (int q = 0; q < 8; ++q) Y0[q] = 0.f;
#pragma unroll
  for (int s = 0; s < NS; ++s) {
    const float4* rec = reinterpret_cast<const float4*>(Gp + ((size_t)s * HW + m) * GK);
#pragma unroll
    for (int k = 0; k < 8; ++k) {
      float4 v = rec[r * 8 + k];
      G0[4 * k + 0] += v.x;
      G0[4 * k + 1] += v.y;
      G0[4 * k + 2] += v.z;
      G0[4 * k + 3] += v.w;
    }
    float4 y0 = rec[256 + r * 2 + 0];
    float4 y1 = rec[256 + r * 2 + 1];
    Y0[0] += y0.x; Y0[1] += y0.y; Y0[2] += y0.z; Y0[3] += y0.w;
    Y0[4] += y1.x; Y0[5] += y1.y; Y0[6] += y1.z; Y0[7] += y1.w;
  }

#pragma unroll
  for (int q = 0; q < 8; ++q) YT_(mi, r, q) = Y0[q];
  __syncthreads();

#pragma unroll
  for (int it = 0; it < 3; ++it) {
    cholqr32(Sm, mi, r);        // CholQR2: orthonormal basis of span(Y)
    cholqr32(Sm, mi, r);
    if (it < 2) {
      // U = G*Q -> WT
      float u[8];
#pragma unroll
      for (int q = 0; q < 8; ++q) {
        float a = 0.f;
#pragma unroll
        for (int b = 0; b < 32; ++b) a = fmaf(G0[b], YT_(mi, b, q), a);
        u[q] = a;
      }
#pragma unroll
      for (int q = 0; q < 8; ++q) WT_(mi, r, q) = u[q];
      __syncthreads();
      // T = Q^T G Q -> SS
#pragma unroll
      for (int e = 0; e < 2; ++e) {
        int idx = r + e * 32, i2 = idx >> 3, j2 = idx & 7;
        float a = 0.f;
#pragma unroll
        for (int b = 0; b < 32; ++b) a = fmaf(YT_(mi, b, i2), WT_(mi, b, j2), a);
        SS_(mi, idx) = a;
      }
      __syncthreads();
      // W = Q R^{-1} -> WT   (implicit qr(A*Q))
      {
        float Rl[36];
        chol8(Sm, mi, Rl);
        trsm1row(Sm, Sm + 4240, mi, r, Rl);
      }
      __syncthreads();
      // Y_next = G*W -> YT
#pragma unroll
      for (int q = 0; q < 8; ++q) {
        float a = 0.f;
#pragma unroll
        for (int b = 0; b < 32; ++b) a = fmaf(G0[b], WT_(mi, b, q), a);
        u[q] = a;
      }
#pragma unroll
      for (int q = 0; q < 8; ++q) YT_(mi, r, q) = u[q];
      __syncthreads();
    }
  }

  // store Q2 row r: Qws[m*256 + r*8 + q]
  float q0[8];
#pragma unroll
  for (int q = 0; q < 8; ++q) q0[q] = YT_(mi, r, q);
  float4* qrec = reinterpret_cast<float4*>(Qws + (size_t)m * 256);
  qrec[r * 2 + 0] = make_float4(q0[0], q0[1], q0[2], q0[3]);
  qrec[r * 2 + 1] = make_float4(q0[4], q0[5], q0[6], q0[7]);
}

// ============ K2 (TM2=32): P = A Q2 (stage1), y = P Q2^T (stage2) ============
// thread = (mi 0..31, g 0..15); stage1: (cj = g&3, qd = g>>2 -> q pair);
// stage2: rows r = g and g+16.
__global__ __launch_bounds__(512, 4) void tsvd_k2(const float* __restrict__ x,
                                                  const float* __restrict__ Qws,
                                                  float* __restrict__ y) {
  __shared__ float Sm2[2 * SLABF2 + TM2 * PST2];
  float* Pl = Sm2 + 2 * SLABF2;
  const int t = threadIdx.x;
  const int mi = t & 31, g = t >> 5;
  const int cj = g & 3, qd = g >> 2;
  const int bid = blockIdx.x;
  const int mt = bid % 98, cq = bid / 98;       // 98 m-tiles x 8 c-slices of 32
  const int m0 = mt * TM2, m = m0 + mi;
  const int cbase = cq * 32;

  // Q2 columns (2qd, 2qd+1) for stage1; Q2 rows g, g+16 for stage2
  const float* qrec = Qws + (size_t)m * 256;
  float Qc0[32], Qc1[32];
#pragma unroll
  for (int b = 0; b < 32; ++b) {
    float2 v = reinterpret_cast<const float2*>(qrec)[b * 4 + qd];
    Qc0[b] = v.x; Qc1[b] = v.y;
  }
  float Qr0[8], Qr1[8];
  {
    float4 a = reinterpret_cast<const float4*>(qrec)[g * 2 + 0];
    float4 b4 = reinterpret_cast<const float4*>(qrec)[g * 2 + 1];
    Qr0[0] = a.x; Qr0[1] = a.y; Qr0[2] = a.z; Qr0[3] = a.w;
    Qr0[4] = b4.x; Qr0[5] = b4.y; Qr0[6] = b4.z; Qr0[7] = b4.w;
    float4 c4 = reinterpret_cast<const float4*>(qrec)[(g + 16) * 2 + 0];
    float4 d4 = reinterpret_cast<const float4*>(qrec)[(g + 16) * 2 + 1];
    Qr1[0] = c4.x; Qr1[1] = c4.y; Qr1[2] = c4.z; Qr1[3] = c4.w;
    Qr1[4] = d4.x; Qr1[5] = d4.y; Qr1[6] = d4.z; Qr1[7] = d4.w;
  }

  float4 st[2];
  stage_load_k2(st, x, cbase, m0, t);
  stage_write_k2(st, Sm2, t);
  for (int ch = 0; ch < 8; ++ch) {              // 8 chunks of CC2=4 c
    if (ch + 1 < 8) stage_load_k2(st, x, cbase + (ch + 1) * CC2, m0, t);
    __syncthreads();                      // slab(ch) ready; P free
    const float* cur = Sm2 + (ch & 1) * SLABF2;
    // ---- stage1: P[mi][cj*8 + 2qd+e] = sum_b x[b][c][m] * Q2[b][2qd+e] ----
    {
      const float* v = cur + cj * SLABC2 + mi * LDP;
      float p0 = 0.f, p1 = 0.f;
#pragma unroll
      for (int k = 0; k < 8; ++k) {
        float4 xb = *reinterpret_cast<const float4*>(v + 4 * k);
        p0 = fmaf(xb.x, Qc0[4 * k + 0], p0);
        p0 = fmaf(xb.y, Qc0[4 * k + 1], p0);
        p0 = fmaf(xb.z, Qc0[4 * k + 2], p0);
        p0 = fmaf(xb.w, Qc0[4 * k + 3], p0);
        p1 = fmaf(xb.x, Qc1[4 * k + 0], p1);
        p1 = fmaf(xb.y, Qc1[4 * k + 1], p1);
        p1 = fmaf(xb.z, Qc1[4 * k + 2], p1);
        p1 = fmaf(xb.w, Qc1[4 * k + 3], p1);
      }
      *reinterpret_cast<float2*>(Pl + mi * PST2 + cj * 8 + 2 * qd) = make_float2(p0, p1);
    }
    if (ch + 1 < 8) stage_write_k2(st, Sm2 + ((ch + 1) & 1) * SLABF2, t);
    __syncthreads();                      // P visible
    // ---- stage2: y[r][c] = sum_q Q2[r][q] * P[c][q], 4 c's x 2 r's ----
    const float* Pm = Pl + mi * PST2;
#pragma unroll
    for (int c2 = 0; c2 < 4; ++c2) {
      float4 pa = *reinterpret_cast<const float4*>(Pm + c2 * 8);
      float4 pb = *reinterpret_cast<const float4*>(Pm + c2 * 8 + 4);
      float a0 = 0.f, a1 = 0.f;
      a0 = fmaf(Qr0[0], pa.x, a0); a1 = fmaf(Qr1[0], pa.x, a1);
      a0 = fmaf(Qr0[1], pa.y, a0); a1 = fmaf(Qr1[1], pa.y, a1);
      a0 = fmaf(Qr0[2], pa.z, a0); a1 = fmaf(Qr1[2], pa.z, a1);
      a0 = fmaf(Qr0[3], pa.w, a0); a1 = fmaf(Qr1[3], pa.w, a1);
      a0 = fmaf(Qr0[4], pb.x, a0); a1 = fmaf(Qr1[4], pb.x, a1);
      a0 = fmaf(Qr0[5], pb.y, a0); a1 = fmaf(Qr1[5], pb.y, a1);
      a0 = fmaf(Qr0[6], pb.z, a0); a1 = fmaf(Qr1[6], pb.z, a1);
      a0 = fmaf(Qr0[7], pb.w, a0); a1 = fmaf(Qr1[7], pb.w, a1);
      const int c = cbase + ch * CC2 + c2;
      y[((size_t)g * NC + c) * HW + m] = a0;         // 128B-coalesced per (r,c)
      y[((size_t)(g + 16) * NC + c) * HW + m] = a1;
    }
  }
}

extern "C" void kernel_launch(void* const* d_in, const int* in_sizes, int n_in,
                              void* d_out, int out_size, void* d_ws, size_t ws_size,
                              hipStream_t stream) {
  const float* x     = (const float*)d_in[0];   // 32*256*3136 fp32
  const float* omega = (const float*)d_in[1];   // 256*8 fp32
  float* y   = (float*)d_out;                   // 32*256*3136 fp32
  float* Qws = (float*)d_ws;                    // 3136*256*4 = 3.21 MB
  // Partial Gram scratch in d_out: 4*3136*1280*4B = 64.2 MB < 102.8 MB;
  // consumed by k1b, then k2 overwrites all of d_out with y.
  float* Gp  = (float*)d_out;

  tsvd_k1a<<<196 * NS, 512, 0, stream>>>(x, omega, Gp);
  tsvd_k1b<<<HW / 8, 256, 0, stream>>>(Gp, Qws);
  tsvd_k2<<<98 * 8, 512, 0, stream>>>(x, Qws, y);
}